// Round 1
// baseline (1778.471 us; speedup 1.0000x reference)
//
#include <hip/hip_runtime.h>
#include <hip/hip_bf16.h>
#include <cstdint>

#define HID 2048
#define FFN 4096
#define NE 16
#define NTOK 2048
#define TOPK 4
#define BM 128
#define BN 128
#define BK 32
#define MAX_TILES 80
#define LDA 40  // padded LDS row stride in ushorts (80B -> stride 20 banks, conflict-light)

typedef __attribute__((ext_vector_type(4))) float f32x4;
typedef __attribute__((ext_vector_type(8))) short bf16x8;

__device__ __forceinline__ ushort f2bf(float f) {
  __hip_bfloat16 h = __float2bfloat16(f);
  return *reinterpret_cast<ushort*>(&h);
}

// ---------------- init: zero per-expert counts ----------------
__global__ void init_kernel(int* __restrict__ counts) {
  if (threadIdx.x < NE) counts[threadIdx.x] = 0;
}

// ---------------- router: logits -> softmax -> top4 -> combine ----------------
__global__ void router_kernel(const float* __restrict__ x, const float* __restrict__ rw,
                              float* __restrict__ wout, float* __restrict__ combine,
                              int* __restrict__ counts) {
  int t = blockIdx.x;
  int tid = threadIdx.x, lane = tid & 63, w = tid >> 6;
  const float* xr = x + (size_t)t * HID;
  const float* r0 = rw + (size_t)(w * 4 + 0) * HID;
  const float* r1 = rw + (size_t)(w * 4 + 1) * HID;
  const float* r2 = rw + (size_t)(w * 4 + 2) * HID;
  const float* r3 = rw + (size_t)(w * 4 + 3) * HID;
  float s0 = 0.f, s1 = 0.f, s2 = 0.f, s3 = 0.f;
  for (int h = lane; h < HID; h += 64) {
    float xv = xr[h];
    s0 += xv * r0[h]; s1 += xv * r1[h]; s2 += xv * r2[h]; s3 += xv * r3[h];
  }
  #pragma unroll
  for (int off = 32; off > 0; off >>= 1) {
    s0 += __shfl_down(s0, off); s1 += __shfl_down(s1, off);
    s2 += __shfl_down(s2, off); s3 += __shfl_down(s3, off);
  }
  __shared__ float logits[NE];
  if (lane == 0) {
    logits[w * 4 + 0] = s0; logits[w * 4 + 1] = s1;
    logits[w * 4 + 2] = s2; logits[w * 4 + 3] = s3;
  }
  __syncthreads();
  if (tid == 0) {
    float p[NE];
    float mx = logits[0];
    #pragma unroll
    for (int e = 1; e < NE; e++) mx = fmaxf(mx, logits[e]);
    float ssum = 0.f;
    #pragma unroll
    for (int e = 0; e < NE; e++) { p[e] = expf(logits[e] - mx); ssum += p[e]; }
    float inv = 1.0f / ssum;
    #pragma unroll
    for (int e = 0; e < NE; e++) { p[e] *= inv; wout[t * NE + e] = p[e]; }
    // top-4, ties -> lowest index first (strict > keeps first max), matching lax.top_k
    int sel[TOPK]; float selw[TOPK];
    unsigned used = 0;
    for (int k = 0; k < TOPK; k++) {
      int best = 0; float bw = -1.0f;
      for (int e = 0; e < NE; e++)
        if (!((used >> e) & 1u) && p[e] > bw) { bw = p[e]; best = e; }
      used |= 1u << best; sel[k] = best; selw[k] = bw;
    }
    float sw = selw[0] + selw[1] + selw[2] + selw[3];
    float invs = 1.0f / sw;
    float comb[NE];
    #pragma unroll
    for (int e = 0; e < NE; e++) comb[e] = 0.f;
    for (int k = 0; k < TOPK; k++) comb[sel[k]] = selw[k] * invs;
    #pragma unroll
    for (int e = 0; e < NE; e++) combine[t * NE + e] = comb[e];
    for (int k = 0; k < TOPK; k++) atomicAdd(&counts[sel[k]], 1);
  }
}

// ---------------- build per-expert segment offsets + tile list ----------------
__global__ void build_tiles_kernel(const int* __restrict__ counts, int* __restrict__ seg_off,
                                   int* __restrict__ tiles, int* __restrict__ ntiles) {
  if (blockIdx.x != 0 || threadIdx.x != 0) return;
  int off = 0, nt = 0;
  for (int e = 0; e < NE; e++) {
    seg_off[e] = off;
    int c = counts[e];
    for (int rb = 0; rb * BM < c; rb++) {
      tiles[nt * 3 + 0] = e;
      tiles[nt * 3 + 1] = off + rb * BM;
      tiles[nt * 3 + 2] = (c - rb * BM < BM) ? (c - rb * BM) : BM;
      nt++;
    }
    off += c;
  }
  seg_off[NE] = off;
  *ntiles = nt;
}

// ---------------- deterministic token list per expert (stable token order) ----------------
__global__ void assign_kernel(const float* __restrict__ combine, const int* __restrict__ seg_off,
                              int* __restrict__ token_flat, float* __restrict__ gate_flat) {
  int e = blockIdx.x;
  int tid = threadIdx.x, lane = tid & 63, w = tid >> 6;
  __shared__ int base;
  __shared__ int wtot[4];
  if (tid == 0) base = seg_off[e];
  __syncthreads();
  for (int t0 = 0; t0 < NTOK; t0 += 256) {
    int t = t0 + tid;
    float g = combine[t * NE + e];
    int flag = (g > 0.0f) ? 1 : 0;
    unsigned long long m = __ballot(flag);
    if (lane == 0) wtot[w] = __popcll(m);
    __syncthreads();
    int pre = 0;
    for (int j = 0; j < w; j++) pre += wtot[j];
    int tot = wtot[0] + wtot[1] + wtot[2] + wtot[3];
    int lp = __popcll(m & ((1ull << lane) - 1ull));
    if (flag) {
      int pos = base + pre + lp;
      token_flat[pos] = t;
      gate_flat[pos] = g;
    }
    __syncthreads();
    if (tid == 0) base += tot;
    __syncthreads();
  }
}

// ---------------- GEMM1 fused: G = silu(X w1) * (X v1), bf16 out ----------------
__global__ __launch_bounds__(256) void mlp1_kernel(
    const float* __restrict__ x, const float* __restrict__ w1, const float* __restrict__ v1,
    const int* __restrict__ tiles, const int* __restrict__ ntiles,
    const int* __restrict__ token_flat, ushort* __restrict__ G) {
  if ((int)blockIdx.x >= *ntiles) return;
  const int e  = tiles[blockIdx.x * 3 + 0];
  const int g0 = tiles[blockIdx.x * 3 + 1];
  const int nr = tiles[blockIdx.x * 3 + 2];
  const int n0 = blockIdx.y * BN;

  __shared__ ushort As[BM * LDA];
  __shared__ ushort Bw[BN * LDA];
  __shared__ ushort Bv[BN * LDA];

  const int tid = threadIdx.x, lane = tid & 63, wv = tid >> 6;
  const int wr = wv >> 1, wc = wv & 1;

  // A staging assignment: 2 threads per row, 16 k each
  const int ar  = tid >> 1;
  const int akh = (tid & 1) * 16;
  const int tok = token_flat[g0 + (ar < nr ? ar : 0)];
  const float* arow = x + (size_t)tok * HID;

  // B staging assignment: thread -> column n, half of k range
  const int bn  = tid & 127;
  const int bkh = (tid >> 7) * 16;
  const float* wcol = w1 + (size_t)e * HID * FFN + n0 + bn;
  const float* vcol = v1 + (size_t)e * HID * FFN + n0 + bn;

  f32x4 acc_h[4][4] = {};
  f32x4 acc_v[4][4] = {};
  const int fr = lane & 15, fk = (lane >> 4) * 8;

  for (int k0 = 0; k0 < HID; k0 += BK) {
    {  // stage A (f32 -> bf16)
      const float4* ap = (const float4*)(arow + k0 + akh);
      float4 a0 = ap[0], a1 = ap[1], a2 = ap[2], a3 = ap[3];
      union { ushort u[8]; uint4 v; } p0, p1;
      p0.u[0] = f2bf(a0.x); p0.u[1] = f2bf(a0.y); p0.u[2] = f2bf(a0.z); p0.u[3] = f2bf(a0.w);
      p0.u[4] = f2bf(a1.x); p0.u[5] = f2bf(a1.y); p0.u[6] = f2bf(a1.z); p0.u[7] = f2bf(a1.w);
      p1.u[0] = f2bf(a2.x); p1.u[1] = f2bf(a2.y); p1.u[2] = f2bf(a2.z); p1.u[3] = f2bf(a2.w);
      p1.u[4] = f2bf(a3.x); p1.u[5] = f2bf(a3.y); p1.u[6] = f2bf(a3.z); p1.u[7] = f2bf(a3.w);
      *(uint4*)&As[ar * LDA + akh]     = p0.v;
      *(uint4*)&As[ar * LDA + akh + 8] = p1.v;
    }
    {  // stage Bw transposed: Bw[n][k]
      float vb[16];
      #pragma unroll
      for (int j = 0; j < 16; j++) vb[j] = wcol[(size_t)(k0 + bkh + j) * FFN];
      union { ushort u[8]; uint4 v; } p0, p1;
      #pragma unroll
      for (int j = 0; j < 8; j++) { p0.u[j] = f2bf(vb[j]); p1.u[j] = f2bf(vb[j + 8]); }
      *(uint4*)&Bw[bn * LDA + bkh]     = p0.v;
      *(uint4*)&Bw[bn * LDA + bkh + 8] = p1.v;
    }
    {  // stage Bv transposed
      float vb[16];
      #pragma unroll
      for (int j = 0; j < 16; j++) vb[j] = vcol[(size_t)(k0 + bkh + j) * FFN];
      union { ushort u[8]; uint4 v; } p0, p1;
      #pragma unroll
      for (int j = 0; j < 8; j++) { p0.u[j] = f2bf(vb[j]); p1.u[j] = f2bf(vb[j + 8]); }
      *(uint4*)&Bv[bn * LDA + bkh]     = p0.v;
      *(uint4*)&Bv[bn * LDA + bkh + 8] = p1.v;
    }
    __syncthreads();
    bf16x8 af[4], bwf[4], bvf[4];
    #pragma unroll
    for (int am = 0; am < 4; am++)
      af[am] = *(const bf16x8*)&As[(wr * 64 + am * 16 + fr) * LDA + fk];
    #pragma unroll
    for (int an = 0; an < 4; an++) {
      bwf[an] = *(const bf16x8*)&Bw[(wc * 64 + an * 16 + fr) * LDA + fk];
      bvf[an] = *(const bf16x8*)&Bv[(wc * 64 + an * 16 + fr) * LDA + fk];
    }
    #pragma unroll
    for (int am = 0; am < 4; am++)
      #pragma unroll
      for (int an = 0; an < 4; an++) {
        acc_h[am][an] = __builtin_amdgcn_mfma_f32_16x16x32_bf16(af[am], bwf[an], acc_h[am][an], 0, 0, 0);
        acc_v[am][an] = __builtin_amdgcn_mfma_f32_16x16x32_bf16(af[am], bvf[an], acc_v[am][an], 0, 0, 0);
      }
    __syncthreads();
  }

  // epilogue: G = silu(h) * v
  #pragma unroll
  for (int am = 0; am < 4; am++) {
    #pragma unroll
    for (int j = 0; j < 4; j++) {
      int m = wr * 64 + am * 16 + (lane >> 4) * 4 + j;
      if (m < nr) {
        ushort* grow = G + (size_t)(g0 + m) * FFN + n0 + wc * 64 + (lane & 15);
        #pragma unroll
        for (int an = 0; an < 4; an++) {
          float h = acc_h[am][an][j];
          float v = acc_v[am][an][j];
          float g = h / (1.0f + __expf(-h)) * v;
          grow[an * 16] = f2bf(g);
        }
      }
    }
  }
}

// ---------------- GEMM2: out += gate * (G w2) ----------------
__global__ __launch_bounds__(256) void mlp2_kernel(
    const ushort* __restrict__ G, const float* __restrict__ w2,
    const int* __restrict__ tiles, const int* __restrict__ ntiles,
    const int* __restrict__ token_flat, const float* __restrict__ gate_flat,
    float* __restrict__ out) {
  if ((int)blockIdx.x >= *ntiles) return;
  const int e  = tiles[blockIdx.x * 3 + 0];
  const int g0 = tiles[blockIdx.x * 3 + 1];
  const int nr = tiles[blockIdx.x * 3 + 2];
  const int n0 = blockIdx.y * BN;

  __shared__ ushort As[BM * LDA];
  __shared__ ushort Bs[BN * LDA];

  const int tid = threadIdx.x, lane = tid & 63, wv = tid >> 6;
  const int wr = wv >> 1, wc = wv & 1;

  const int ar  = tid >> 1;
  const int akh = (tid & 1) * 16;
  const ushort* arow = G + (size_t)(g0 + (ar < nr ? ar : 0)) * FFN;

  const int bn  = tid & 127;
  const int bkh = (tid >> 7) * 16;
  const float* wcol = w2 + (size_t)e * FFN * HID + n0 + bn;

  f32x4 acc[4][4] = {};
  const int fr = lane & 15, fk = (lane >> 4) * 8;

  for (int k0 = 0; k0 < FFN; k0 += BK) {
    {  // stage A (already bf16)
      const uint4* gp = (const uint4*)(arow + k0 + akh);
      uint4 v0 = gp[0], v1 = gp[1];
      *(uint4*)&As[ar * LDA + akh]     = v0;
      *(uint4*)&As[ar * LDA + akh + 8] = v1;
    }
    {  // stage B transposed
      float vb[16];
      #pragma unroll
      for (int j = 0; j < 16; j++) vb[j] = wcol[(size_t)(k0 + bkh + j) * HID];
      union { ushort u[8]; uint4 v; } p0, p1;
      #pragma unroll
      for (int j = 0; j < 8; j++) { p0.u[j] = f2bf(vb[j]); p1.u[j] = f2bf(vb[j + 8]); }
      *(uint4*)&Bs[bn * LDA + bkh]     = p0.v;
      *(uint4*)&Bs[bn * LDA + bkh + 8] = p1.v;
    }
    __syncthreads();
    bf16x8 af[4], bf_[4];
    #pragma unroll
    for (int am = 0; am < 4; am++)
      af[am] = *(const bf16x8*)&As[(wr * 64 + am * 16 + fr) * LDA + fk];
    #pragma unroll
    for (int an = 0; an < 4; an++)
      bf_[an] = *(const bf16x8*)&Bs[(wc * 64 + an * 16 + fr) * LDA + fk];
    #pragma unroll
    for (int am = 0; am < 4; am++)
      #pragma unroll
      for (int an = 0; an < 4; an++)
        acc[am][an] = __builtin_amdgcn_mfma_f32_16x16x32_bf16(af[am], bf_[an], acc[am][an], 0, 0, 0);
    __syncthreads();
  }

  #pragma unroll
  for (int am = 0; am < 4; am++) {
    #pragma unroll
    for (int j = 0; j < 4; j++) {
      int m = wr * 64 + am * 16 + (lane >> 4) * 4 + j;
      if (m < nr) {
        float gate = gate_flat[g0 + m];
        int tok = token_flat[g0 + m];
        float* orow = out + (size_t)tok * HID + n0 + wc * 64 + (lane & 15);
        #pragma unroll
        for (int an = 0; an < 4; an++)
          atomicAdd(&orow[an * 16], acc[am][an][j] * gate);
      }
    }
  }
}

// ---------------- launch ----------------
extern "C" void kernel_launch(void* const* d_in, const int* in_sizes, int n_in,
                              void* d_out, int out_size, void* d_ws, size_t ws_size,
                              hipStream_t stream) {
  const float* x  = (const float*)d_in[0];
  const float* rw = (const float*)d_in[1];
  const float* w1 = (const float*)d_in[2];
  const float* v1 = (const float*)d_in[3];
  const float* w2 = (const float*)d_in[4];
  float* out0 = (float*)d_out;
  float* wout = out0 + (size_t)NTOK * HID;

  char* ws = (char*)d_ws;
  float* combine    = (float*)(ws + 0);        // 2048*16*4 = 131072
  int*   counts     = (int*)(ws + 131072);     // 64
  int*   seg_off    = (int*)(ws + 131200);     // 68
  int*   ntiles     = (int*)(ws + 131328);     // 4
  int*   tiles      = (int*)(ws + 131392);     // 960
  int*   token_flat = (int*)(ws + 132352);     // 32768
  float* gate_flat  = (float*)(ws + 165120);   // 32768
  ushort* G         = (ushort*)(ws + 262144);  // 8192*4096*2 = 64 MB

  hipMemsetAsync(d_out, 0, (size_t)out_size * sizeof(float), stream);
  init_kernel<<<1, 64, 0, stream>>>(counts);
  router_kernel<<<NTOK, 256, 0, stream>>>(x, rw, wout, combine, counts);
  build_tiles_kernel<<<1, 1, 0, stream>>>(counts, seg_off, tiles, ntiles);
  assign_kernel<<<NE, 256, 0, stream>>>(combine, seg_off, token_flat, gate_flat);
  mlp1_kernel<<<dim3(MAX_TILES, FFN / BN), 256, 0, stream>>>(x, w1, v1, tiles, ntiles, token_flat, G);
  mlp2_kernel<<<dim3(MAX_TILES, HID / BN), 256, 0, stream>>>(G, w2, tiles, ntiles, token_flat, gate_flat, out0);
}

// Round 2
// 1515.793 us; speedup vs baseline: 1.1733x; 1.1733x over previous
//
#include <hip/hip_runtime.h>
#include <hip/hip_bf16.h>
#include <cstdint>

#define HID 2048
#define FFN 4096
#define NE 16
#define NTOK 2048
#define TOPK 4
#define BM 128
#define BN 64
#define BK 64
#define MAX_TILES 80
#define TOTROWS 8192

typedef __attribute__((ext_vector_type(4))) float f32x4;
typedef __attribute__((ext_vector_type(8))) short bf16x8;

__device__ __forceinline__ ushort f2bf(float f) {
  __hip_bfloat16 h = __float2bfloat16(f);
  return *reinterpret_cast<ushort*>(&h);
}

__device__ __forceinline__ int swz(int row) { return (row ^ (row >> 2)) & 7; }

__device__ __forceinline__ void gload_lds16(const void* g, void* l) {
  __builtin_amdgcn_global_load_lds((const __attribute__((address_space(1))) void*)g,
                                   (__attribute__((address_space(3))) void*)l, 16, 0, 0);
}

// ---------------- init ----------------
__global__ void init_kernel(int* __restrict__ counts) {
  if (threadIdx.x < NE) counts[threadIdx.x] = 0;
}

// ---------------- x -> bf16 ----------------
__global__ void cvt_x_kernel(const float* __restrict__ x, ushort* __restrict__ xbf) {
  int i = blockIdx.x * 256 + threadIdx.x;
  float4 v = ((const float4*)x)[i];
  ushort4 o;
  o.x = f2bf(v.x); o.y = f2bf(v.y); o.z = f2bf(v.z); o.w = f2bf(v.w);
  ((ushort4*)xbf)[i] = o;
}

// ---------------- router ----------------
__global__ void router_kernel(const float* __restrict__ x, const float* __restrict__ rw,
                              float* __restrict__ wout, float* __restrict__ combine,
                              int* __restrict__ counts) {
  int t = blockIdx.x;
  int tid = threadIdx.x, lane = tid & 63, w = tid >> 6;
  const float* xr = x + (size_t)t * HID;
  const float* r0 = rw + (size_t)(w * 4 + 0) * HID;
  const float* r1 = rw + (size_t)(w * 4 + 1) * HID;
  const float* r2 = rw + (size_t)(w * 4 + 2) * HID;
  const float* r3 = rw + (size_t)(w * 4 + 3) * HID;
  float s0 = 0.f, s1 = 0.f, s2 = 0.f, s3 = 0.f;
  for (int h = lane; h < HID; h += 64) {
    float xv = xr[h];
    s0 += xv * r0[h]; s1 += xv * r1[h]; s2 += xv * r2[h]; s3 += xv * r3[h];
  }
  #pragma unroll
  for (int off = 32; off > 0; off >>= 1) {
    s0 += __shfl_down(s0, off); s1 += __shfl_down(s1, off);
    s2 += __shfl_down(s2, off); s3 += __shfl_down(s3, off);
  }
  __shared__ float logits[NE];
  if (lane == 0) {
    logits[w * 4 + 0] = s0; logits[w * 4 + 1] = s1;
    logits[w * 4 + 2] = s2; logits[w * 4 + 3] = s3;
  }
  __syncthreads();
  if (tid == 0) {
    float p[NE];
    float mx = logits[0];
    #pragma unroll
    for (int e = 1; e < NE; e++) mx = fmaxf(mx, logits[e]);
    float ssum = 0.f;
    #pragma unroll
    for (int e = 0; e < NE; e++) { p[e] = expf(logits[e] - mx); ssum += p[e]; }
    float inv = 1.0f / ssum;
    #pragma unroll
    for (int e = 0; e < NE; e++) { p[e] *= inv; wout[t * NE + e] = p[e]; }
    int sel[TOPK]; float selw[TOPK];
    unsigned used = 0;
    for (int k = 0; k < TOPK; k++) {
      int best = 0; float bw = -1.0f;
      for (int e = 0; e < NE; e++)
        if (!((used >> e) & 1u) && p[e] > bw) { bw = p[e]; best = e; }
      used |= 1u << best; sel[k] = best; selw[k] = bw;
    }
    float sw = selw[0] + selw[1] + selw[2] + selw[3];
    float invs = 1.0f / sw;
    float comb[NE];
    #pragma unroll
    for (int e = 0; e < NE; e++) comb[e] = 0.f;
    for (int k = 0; k < TOPK; k++) comb[sel[k]] = selw[k] * invs;
    #pragma unroll
    for (int e = 0; e < NE; e++) combine[t * NE + e] = comb[e];
    for (int k = 0; k < TOPK; k++) atomicAdd(&counts[sel[k]], 1);
  }
}

// ---------------- tiles ----------------
__global__ void build_tiles_kernel(const int* __restrict__ counts, int* __restrict__ seg_off,
                                   int* __restrict__ tiles, int* __restrict__ ntiles) {
  if (blockIdx.x != 0 || threadIdx.x != 0) return;
  int off = 0, nt = 0;
  for (int e = 0; e < NE; e++) {
    seg_off[e] = off;
    int c = counts[e];
    for (int rb = 0; rb * BM < c; rb++) {
      tiles[nt * 3 + 0] = e;
      tiles[nt * 3 + 1] = off + rb * BM;
      tiles[nt * 3 + 2] = (c - rb * BM < BM) ? (c - rb * BM) : BM;
      nt++;
    }
    off += c;
  }
  seg_off[NE] = off;
  *ntiles = nt;
}

// ---------------- token assignment ----------------
__global__ void assign_kernel(const float* __restrict__ combine, const int* __restrict__ seg_off,
                              int* __restrict__ token_flat, float* __restrict__ gate_flat) {
  int e = blockIdx.x;
  int tid = threadIdx.x, lane = tid & 63, w = tid >> 6;
  __shared__ int base;
  __shared__ int wtot[4];
  if (tid == 0) base = seg_off[e];
  __syncthreads();
  for (int t0 = 0; t0 < NTOK; t0 += 256) {
    int t = t0 + tid;
    float g = combine[t * NE + e];
    int flag = (g > 0.0f) ? 1 : 0;
    unsigned long long m = __ballot(flag);
    if (lane == 0) wtot[w] = __popcll(m);
    __syncthreads();
    int pre = 0;
    for (int j = 0; j < w; j++) pre += wtot[j];
    int tot = wtot[0] + wtot[1] + wtot[2] + wtot[3];
    int lp = __popcll(m & ((1ull << lane) - 1ull));
    if (flag) {
      int pos = base + pre + lp;
      token_flat[pos] = t;
      gate_flat[pos] = g;
    }
    __syncthreads();
    if (tid == 0) base += tot;
    __syncthreads();
  }
}

// ---------------- GEMM1 fused: G = silu(X w1) * (X v1) ----------------
__global__ __launch_bounds__(256) void mlp1_kernel(
    const ushort* __restrict__ xbf, const float* __restrict__ w1, const float* __restrict__ v1,
    const int* __restrict__ tiles, const int* __restrict__ ntiles,
    const int* __restrict__ token_flat, ushort* __restrict__ G) {
  if ((int)blockIdx.x >= *ntiles) return;
  const int e  = tiles[blockIdx.x * 3 + 0];
  const int g0 = tiles[blockIdx.x * 3 + 1];
  const int nr = tiles[blockIdx.x * 3 + 2];
  const int n0 = blockIdx.y * BN;

  __shared__ __align__(16) ushort As[BM * BK];  // 16 KB, rows 128B, swizzled 16B granules
  __shared__ __align__(16) ushort Bw[BN * BK];  // 8 KB
  __shared__ __align__(16) ushort Bv[BN * BK];  // 8 KB

  const int tid = threadIdx.x, lane = tid & 63, wv = tid >> 6;
  const int wr = wv >> 1, wc = wv & 1;

  // A staging: 4 global_load_lds(16B)/thread, pre-swizzled source
  const ushort* asrc[4];
  ushort* adst[4];
  #pragma unroll
  for (int i = 0; i < 4; i++) {
    int slot = i * 256 + tid;
    int m = slot >> 3, g = slot & 7;
    int r = m < nr ? m : (nr - 1);
    int tok = token_flat[g0 + r];
    asrc[i] = xbf + (size_t)tok * HID + ((g ^ swz(m)) << 3);
    adst[i] = (ushort*)As + slot * 8;
  }

  // B staging: thread owns 4 n (nq*4..+3) x 4 k (kb4*4..+3)
  const int nq = tid & 15, kb4 = tid >> 4;
  const float* wsrc = w1 + (size_t)e * HID * FFN + (size_t)kb4 * 4 * FFN + n0 + nq * 4;
  const float* vsrc = v1 + (size_t)e * HID * FFN + (size_t)kb4 * 4 * FFN + n0 + nq * 4;
  uint boff[4];
  #pragma unroll
  for (int c = 0; c < 4; c++) {
    int n = nq * 4 + c;
    boff[c] = (uint)(n * 128 + (((kb4 >> 1) ^ swz(n)) << 4) + ((kb4 & 1) << 3));
  }

  f32x4 acc_h[4][2] = {};
  f32x4 acc_v[4][2] = {};
  const int fr = lane & 15, fq = lane >> 4;

  for (int k0 = 0; k0 < HID; k0 += BK) {
    // A: async DMA first
    #pragma unroll
    for (int i = 0; i < 4; i++)
      gload_lds16(asrc[i] + k0, adst[i]);
    // Bw: load -> cvt -> swizzled write
    {
      size_t kbase = (size_t)k0 * FFN;
      float4 r0 = *(const float4*)(wsrc + kbase);
      float4 r1 = *(const float4*)(wsrc + kbase + FFN);
      float4 r2 = *(const float4*)(wsrc + kbase + 2 * FFN);
      float4 r3 = *(const float4*)(wsrc + kbase + 3 * FFN);
      const float* rr[4] = {(const float*)&r0, (const float*)&r1, (const float*)&r2, (const float*)&r3};
      #pragma unroll
      for (int c = 0; c < 4; c++) {
        union { ushort u[4]; uint2 v; } p;
        #pragma unroll
        for (int j = 0; j < 4; j++) p.u[j] = f2bf(rr[j][c]);
        *(uint2*)((char*)Bw + boff[c]) = p.v;
      }
    }
    // Bv
    {
      size_t kbase = (size_t)k0 * FFN;
      float4 r0 = *(const float4*)(vsrc + kbase);
      float4 r1 = *(const float4*)(vsrc + kbase + FFN);
      float4 r2 = *(const float4*)(vsrc + kbase + 2 * FFN);
      float4 r3 = *(const float4*)(vsrc + kbase + 3 * FFN);
      const float* rr[4] = {(const float*)&r0, (const float*)&r1, (const float*)&r2, (const float*)&r3};
      #pragma unroll
      for (int c = 0; c < 4; c++) {
        union { ushort u[4]; uint2 v; } p;
        #pragma unroll
        for (int j = 0; j < 4; j++) p.u[j] = f2bf(rr[j][c]);
        *(uint2*)((char*)Bv + boff[c]) = p.v;
      }
    }
    __syncthreads();
    #pragma unroll
    for (int half = 0; half < 2; half++) {
      bf16x8 af[4], bwf[2], bvf[2];
      #pragma unroll
      for (int am = 0; am < 4; am++) {
        int m = wr * 64 + am * 16 + fr;
        af[am] = *(const bf16x8*)((const char*)As + m * 128 + (((half * 4 + fq) ^ swz(m)) << 4));
      }
      #pragma unroll
      for (int an = 0; an < 2; an++) {
        int n = wc * 32 + an * 16 + fr;
        int off = n * 128 + (((half * 4 + fq) ^ swz(n)) << 4);
        bwf[an] = *(const bf16x8*)((const char*)Bw + off);
        bvf[an] = *(const bf16x8*)((const char*)Bv + off);
      }
      #pragma unroll
      for (int am = 0; am < 4; am++)
        #pragma unroll
        for (int an = 0; an < 2; an++) {
          acc_h[am][an] = __builtin_amdgcn_mfma_f32_16x16x32_bf16(af[am], bwf[an], acc_h[am][an], 0, 0, 0);
          acc_v[am][an] = __builtin_amdgcn_mfma_f32_16x16x32_bf16(af[am], bvf[an], acc_v[am][an], 0, 0, 0);
        }
    }
    __syncthreads();
  }

  // epilogue: G = silu(h) * v
  #pragma unroll
  for (int am = 0; am < 4; am++) {
    #pragma unroll
    for (int j = 0; j < 4; j++) {
      int m = wr * 64 + am * 16 + fq * 4 + j;
      if (m < nr) {
        ushort* grow = G + (size_t)(g0 + m) * FFN + n0 + wc * 32 + fr;
        #pragma unroll
        for (int an = 0; an < 2; an++) {
          float h = acc_h[am][an][j];
          float v = acc_v[am][an][j];
          float g = h / (1.0f + __expf(-h)) * v;
          grow[an * 16] = f2bf(g);
        }
      }
    }
  }
}

// ---------------- GEMM2: out += gate * (G w2) ----------------
__global__ __launch_bounds__(256) void mlp2_kernel(
    const ushort* __restrict__ G, const float* __restrict__ w2,
    const int* __restrict__ tiles, const int* __restrict__ ntiles,
    const int* __restrict__ token_flat, const float* __restrict__ gate_flat,
    float* __restrict__ out) {
  if ((int)blockIdx.x >= *ntiles) return;
  const int e  = tiles[blockIdx.x * 3 + 0];
  const int g0 = tiles[blockIdx.x * 3 + 1];
  const int nr = tiles[blockIdx.x * 3 + 2];
  const int n0 = blockIdx.y * BN;

  __shared__ __align__(16) ushort As[BM * BK];  // 16 KB
  __shared__ __align__(16) ushort Bs[BN * BK];  // 8 KB

  const int tid = threadIdx.x, lane = tid & 63, wv = tid >> 6;
  const int wr = wv >> 1, wc = wv & 1;

  const ushort* asrc[4];
  ushort* adst[4];
  #pragma unroll
  for (int i = 0; i < 4; i++) {
    int slot = i * 256 + tid;
    int m = slot >> 3, g = slot & 7;
    int gr = g0 + m;
    if (gr > TOTROWS - 1) gr = TOTROWS - 1;
    asrc[i] = G + (size_t)gr * FFN + ((g ^ swz(m)) << 3);
    adst[i] = (ushort*)As + slot * 8;
  }

  const int nq = tid & 15, kb4 = tid >> 4;
  const float* wsrc = w2 + (size_t)e * FFN * HID + (size_t)kb4 * 4 * HID + n0 + nq * 4;
  uint boff[4];
  #pragma unroll
  for (int c = 0; c < 4; c++) {
    int n = nq * 4 + c;
    boff[c] = (uint)(n * 128 + (((kb4 >> 1) ^ swz(n)) << 4) + ((kb4 & 1) << 3));
  }

  f32x4 acc[4][2] = {};
  const int fr = lane & 15, fq = lane >> 4;

  for (int k0 = 0; k0 < FFN; k0 += BK) {
    #pragma unroll
    for (int i = 0; i < 4; i++)
      gload_lds16(asrc[i] + k0, adst[i]);
    {
      size_t kbase = (size_t)k0 * HID;
      float4 r0 = *(const float4*)(wsrc + kbase);
      float4 r1 = *(const float4*)(wsrc + kbase + HID);
      float4 r2 = *(const float4*)(wsrc + kbase + 2 * HID);
      float4 r3 = *(const float4*)(wsrc + kbase + 3 * HID);
      const float* rr[4] = {(const float*)&r0, (const float*)&r1, (const float*)&r2, (const float*)&r3};
      #pragma unroll
      for (int c = 0; c < 4; c++) {
        union { ushort u[4]; uint2 v; } p;
        #pragma unroll
        for (int j = 0; j < 4; j++) p.u[j] = f2bf(rr[j][c]);
        *(uint2*)((char*)Bs + boff[c]) = p.v;
      }
    }
    __syncthreads();
    #pragma unroll
    for (int half = 0; half < 2; half++) {
      bf16x8 af[4], bf_[2];
      #pragma unroll
      for (int am = 0; am < 4; am++) {
        int m = wr * 64 + am * 16 + fr;
        af[am] = *(const bf16x8*)((const char*)As + m * 128 + (((half * 4 + fq) ^ swz(m)) << 4));
      }
      #pragma unroll
      for (int an = 0; an < 2; an++) {
        int n = wc * 32 + an * 16 + fr;
        bf_[an] = *(const bf16x8*)((const char*)Bs + n * 128 + (((half * 4 + fq) ^ swz(n)) << 4));
      }
      #pragma unroll
      for (int am = 0; am < 4; am++)
        #pragma unroll
        for (int an = 0; an < 2; an++)
          acc[am][an] = __builtin_amdgcn_mfma_f32_16x16x32_bf16(af[am], bf_[an], acc[am][an], 0, 0, 0);
    }
    __syncthreads();
  }

  #pragma unroll
  for (int am = 0; am < 4; am++) {
    #pragma unroll
    for (int j = 0; j < 4; j++) {
      int m = wr * 64 + am * 16 + fq * 4 + j;
      if (m < nr) {
        float gate = gate_flat[g0 + m];
        int tok = token_flat[g0 + m];
        float* orow = out + (size_t)tok * HID + n0 + wc * 32 + fr;
        #pragma unroll
        for (int an = 0; an < 2; an++)
          atomicAdd(&orow[an * 16], acc[am][an][j] * gate);
      }
    }
  }
}

// ---------------- launch ----------------
extern "C" void kernel_launch(void* const* d_in, const int* in_sizes, int n_in,
                              void* d_out, int out_size, void* d_ws, size_t ws_size,
                              hipStream_t stream) {
  const float* x  = (const float*)d_in[0];
  const float* rw = (const float*)d_in[1];
  const float* w1 = (const float*)d_in[2];
  const float* v1 = (const float*)d_in[3];
  const float* w2 = (const float*)d_in[4];
  float* out0 = (float*)d_out;
  float* wout = out0 + (size_t)NTOK * HID;

  char* ws = (char*)d_ws;
  float* combine    = (float*)(ws + 0);        // 131072 B
  int*   counts     = (int*)(ws + 131072);
  int*   seg_off    = (int*)(ws + 131200);
  int*   ntiles     = (int*)(ws + 131328);
  int*   tiles      = (int*)(ws + 131392);
  int*   token_flat = (int*)(ws + 132352);
  float* gate_flat  = (float*)(ws + 165120);
  ushort* G         = (ushort*)(ws + 262144);              // 64 MB
  ushort* xbf       = (ushort*)(ws + 262144 + (size_t)TOTROWS * FFN * 2);  // 8 MB

  hipMemsetAsync(d_out, 0, (size_t)out_size * sizeof(float), stream);
  init_kernel<<<1, 64, 0, stream>>>(counts);
  cvt_x_kernel<<<(NTOK * HID / 4) / 256, 256, 0, stream>>>(x, (ushort*)xbf);
  router_kernel<<<NTOK, 256, 0, stream>>>(x, rw, wout, combine, counts);
  build_tiles_kernel<<<1, 1, 0, stream>>>(counts, seg_off, tiles, ntiles);
  assign_kernel<<<NE, 256, 0, stream>>>(combine, seg_off, token_flat, gate_flat);
  mlp1_kernel<<<dim3(MAX_TILES, FFN / BN), 256, 0, stream>>>(xbf, w1, v1, tiles, ntiles, token_flat, G);
  mlp2_kernel<<<dim3(MAX_TILES, HID / BN), 256, 0, stream>>>(G, w2, tiles, ntiles, token_flat, gate_flat, out0);
}

// Round 3
// 989.658 us; speedup vs baseline: 1.7971x; 1.5316x over previous
//
#include <hip/hip_runtime.h>
#include <hip/hip_bf16.h>
#include <cstdint>

#define HID 2048
#define FFN 4096
#define NE 16
#define NTOK 2048
#define TOPK 4
#define BM 256
#define BN 64
#define BK 64
#define MAXT 48
#define TOTROWS 8192
#define GRID1 (MAXT * (FFN / BN))   // 48*64 = 3072
#define GRID2 (MAXT * (HID / BN))   // 48*32 = 1536
#define CHUNK1 (GRID1 / 8)
#define CHUNK2 (GRID2 / 8)

typedef __attribute__((ext_vector_type(4))) float f32x4;
typedef __attribute__((ext_vector_type(8))) short bf16x8;

__device__ __forceinline__ ushort f2bf(float f) {
  __hip_bfloat16 h = __float2bfloat16(f);
  return *reinterpret_cast<ushort*>(&h);
}

__device__ __forceinline__ int swz(int row) { return (row ^ (row >> 2)) & 7; }

__device__ __forceinline__ void gload_lds16(const void* g, void* l) {
  __builtin_amdgcn_global_load_lds((const __attribute__((address_space(1))) void*)g,
                                   (__attribute__((address_space(3))) void*)l, 16, 0, 0);
}

// ---------------- init ----------------
__global__ void init_kernel(int* __restrict__ counts) {
  if (threadIdx.x < NE) counts[threadIdx.x] = 0;
}

// ---------------- x -> bf16 ----------------
__global__ void cvt_x_kernel(const float* __restrict__ x, ushort* __restrict__ xbf) {
  int i = blockIdx.x * 256 + threadIdx.x;
  float4 v = ((const float4*)x)[i];
  ushort4 o;
  o.x = f2bf(v.x); o.y = f2bf(v.y); o.z = f2bf(v.z); o.w = f2bf(v.w);
  ((ushort4*)xbf)[i] = o;
}

// ---------------- router ----------------
__global__ void router_kernel(const float* __restrict__ x, const float* __restrict__ rw,
                              float* __restrict__ wout, float* __restrict__ combine,
                              int* __restrict__ counts) {
  int t = blockIdx.x;
  int tid = threadIdx.x, lane = tid & 63, w = tid >> 6;
  const float* xr = x + (size_t)t * HID;
  const float* r0 = rw + (size_t)(w * 4 + 0) * HID;
  const float* r1 = rw + (size_t)(w * 4 + 1) * HID;
  const float* r2 = rw + (size_t)(w * 4 + 2) * HID;
  const float* r3 = rw + (size_t)(w * 4 + 3) * HID;
  float s0 = 0.f, s1 = 0.f, s2 = 0.f, s3 = 0.f;
  for (int h = lane; h < HID; h += 64) {
    float xv = xr[h];
    s0 += xv * r0[h]; s1 += xv * r1[h]; s2 += xv * r2[h]; s3 += xv * r3[h];
  }
  #pragma unroll
  for (int off = 32; off > 0; off >>= 1) {
    s0 += __shfl_down(s0, off); s1 += __shfl_down(s1, off);
    s2 += __shfl_down(s2, off); s3 += __shfl_down(s3, off);
  }
  __shared__ float logits[NE];
  if (lane == 0) {
    logits[w * 4 + 0] = s0; logits[w * 4 + 1] = s1;
    logits[w * 4 + 2] = s2; logits[w * 4 + 3] = s3;
  }
  __syncthreads();
  if (tid == 0) {
    float p[NE];
    float mx = logits[0];
    #pragma unroll
    for (int e = 1; e < NE; e++) mx = fmaxf(mx, logits[e]);
    float ssum = 0.f;
    #pragma unroll
    for (int e = 0; e < NE; e++) { p[e] = expf(logits[e] - mx); ssum += p[e]; }
    float inv = 1.0f / ssum;
    #pragma unroll
    for (int e = 0; e < NE; e++) { p[e] *= inv; wout[t * NE + e] = p[e]; }
    int sel[TOPK]; float selw[TOPK];
    unsigned used = 0;
    for (int k = 0; k < TOPK; k++) {
      int best = 0; float bw = -1.0f;
      for (int e = 0; e < NE; e++)
        if (!((used >> e) & 1u) && p[e] > bw) { bw = p[e]; best = e; }
      used |= 1u << best; sel[k] = best; selw[k] = bw;
    }
    float sw = selw[0] + selw[1] + selw[2] + selw[3];
    float invs = 1.0f / sw;
    float comb[NE];
    #pragma unroll
    for (int e = 0; e < NE; e++) comb[e] = 0.f;
    for (int k = 0; k < TOPK; k++) comb[sel[k]] = selw[k] * invs;
    #pragma unroll
    for (int e = 0; e < NE; e++) combine[t * NE + e] = comb[e];
    for (int k = 0; k < TOPK; k++) atomicAdd(&counts[sel[k]], 1);
  }
}

// ---------------- tiles (BM=256) ----------------
__global__ void build_tiles_kernel(const int* __restrict__ counts, int* __restrict__ seg_off,
                                   int* __restrict__ tiles, int* __restrict__ ntiles) {
  if (blockIdx.x != 0 || threadIdx.x != 0) return;
  int off = 0, nt = 0;
  for (int e = 0; e < NE; e++) {
    seg_off[e] = off;
    int c = counts[e];
    for (int rb = 0; rb * BM < c; rb++) {
      tiles[nt * 3 + 0] = e;
      tiles[nt * 3 + 1] = off + rb * BM;
      tiles[nt * 3 + 2] = (c - rb * BM < BM) ? (c - rb * BM) : BM;
      nt++;
    }
    off += c;
  }
  seg_off[NE] = off;
  *ntiles = nt;
}

// ---------------- token assignment ----------------
__global__ void assign_kernel(const float* __restrict__ combine, const int* __restrict__ seg_off,
                              int* __restrict__ token_flat, float* __restrict__ gate_flat) {
  int e = blockIdx.x;
  int tid = threadIdx.x, lane = tid & 63, w = tid >> 6;
  __shared__ int base;
  __shared__ int wtot[4];
  if (tid == 0) base = seg_off[e];
  __syncthreads();
  for (int t0 = 0; t0 < NTOK; t0 += 256) {
    int t = t0 + tid;
    float g = combine[t * NE + e];
    int flag = (g > 0.0f) ? 1 : 0;
    unsigned long long m = __ballot(flag);
    if (lane == 0) wtot[w] = __popcll(m);
    __syncthreads();
    int pre = 0;
    for (int j = 0; j < w; j++) pre += wtot[j];
    int tot = wtot[0] + wtot[1] + wtot[2] + wtot[3];
    int lp = __popcll(m & ((1ull << lane) - 1ull));
    if (flag) {
      int pos = base + pre + lp;
      token_flat[pos] = t;
      gate_flat[pos] = g;
    }
    __syncthreads();
    if (tid == 0) base += tot;
    __syncthreads();
  }
}

// ---------------- GEMM1 fused: G = silu(X w1) * (X v1) ----------------
__global__ __launch_bounds__(512, 4) void mlp1_kernel(
    const ushort* __restrict__ xbf, const float* __restrict__ w1, const float* __restrict__ v1,
    const int* __restrict__ tiles, const int* __restrict__ ntiles,
    const int* __restrict__ token_flat, ushort* __restrict__ G) {
  // XCD-chunked bijective swizzle, tile-fastest within chunk
  int id = blockIdx.x;
  int wg = (id & 7) * CHUNK1 + (id >> 3);
  int tile = wg % MAXT, nblk = wg / MAXT;
  if (tile >= *ntiles) return;
  const int e  = tiles[tile * 3 + 0];
  const int g0 = tiles[tile * 3 + 1];
  const int nr = tiles[tile * 3 + 2];
  const int n0 = nblk * BN;

  __shared__ __align__(16) ushort As[2][BM * BK];  // 2 x 32 KB
  __shared__ __align__(16) ushort Bw[BN * BK];     // 8 KB
  __shared__ __align__(16) ushort Bv[BN * BK];     // 8 KB

  const int tid = threadIdx.x, lane = tid & 63, wv = tid >> 6;
  const int wr = wv >> 1, wc = wv & 1;
  const int fr = lane & 15, fq = lane >> 4;

  // A: 4 slots/thread, swizzled global source, linear LDS dest
  uint aoff[4];
  int aslot[4];
  #pragma unroll
  for (int i = 0; i < 4; i++) {
    int slot = i * 512 + tid;
    int m = slot >> 3, g = slot & 7;
    int r = m < nr ? m : (nr - 1);
    int tok = token_flat[g0 + r];
    aoff[i] = (uint)(tok * HID + ((g ^ swz(m)) << 3));
    aslot[i] = slot * 8;
  }

  // B: half the threads stage w, half stage v. slot = 4n-cols x 4k-rows
  const int bs = tid & 255;
  const int bnq = bs & 15, bkq = bs >> 4;  // bkq in 0..15
  const float* bsrc = ((tid >> 8) ? v1 : w1) + (size_t)e * HID * FFN + (size_t)(bkq * 4) * FFN + n0 + bnq * 4;
  ushort* bdst = (tid >> 8) ? Bv : Bw;
  uint boff[4];
  #pragma unroll
  for (int c = 0; c < 4; c++) {
    int n = bnq * 4 + c;
    boff[c] = (uint)(n * 128 + (((bkq >> 1) ^ swz(n)) << 4) + ((bkq & 1) << 3));
  }

  float4 br0, br1, br2, br3;
  #define LOADB(k0) { size_t kb = (size_t)(k0) * FFN; \
      br0 = *(const float4*)(bsrc + kb); br1 = *(const float4*)(bsrc + kb + FFN); \
      br2 = *(const float4*)(bsrc + kb + 2 * FFN); br3 = *(const float4*)(bsrc + kb + 3 * FFN); }
  #define WRITEB() { const float* rr[4] = {(const float*)&br0, (const float*)&br1, (const float*)&br2, (const float*)&br3}; \
      _Pragma("unroll") for (int c = 0; c < 4; c++) { \
        union { ushort u[4]; uint2 v; } p; \
        _Pragma("unroll") for (int j = 0; j < 4; j++) p.u[j] = f2bf(rr[j][c]); \
        *(uint2*)((char*)bdst + boff[c]) = p.v; } }

  // prologue: stage tile 0
  LOADB(0);
  #pragma unroll
  for (int i = 0; i < 4; i++)
    gload_lds16(xbf + aoff[i], &As[0][aslot[i]]);
  WRITEB();
  __syncthreads();

  f32x4 acc_h[4][2] = {};
  f32x4 acc_v[4][2] = {};
  int cur = 0;

  for (int t = 0; t < HID / BK; t++) {
    const int last = (t == HID / BK - 1);
    if (!last) {
      int kn = (t + 1) * BK;
      LOADB(kn);
      ushort* abase = &As[cur ^ 1][0];
      #pragma unroll
      for (int i = 0; i < 4; i++)
        gload_lds16(xbf + aoff[i] + kn, abase + aslot[i]);
    }
    const char* Ab = (const char*)&As[cur][0];
    #pragma unroll
    for (int hk = 0; hk < 2; hk++) {
      bf16x8 af[4], bwf[2], bvf[2];
      #pragma unroll
      for (int am = 0; am < 4; am++) {
        int m = wr * 64 + am * 16 + fr;
        af[am] = *(const bf16x8*)(Ab + m * 128 + (((hk * 4 + fq) ^ swz(m)) << 4));
      }
      #pragma unroll
      for (int an = 0; an < 2; an++) {
        int n = wc * 32 + an * 16 + fr;
        int off = n * 128 + (((hk * 4 + fq) ^ swz(n)) << 4);
        bwf[an] = *(const bf16x8*)((const char*)Bw + off);
        bvf[an] = *(const bf16x8*)((const char*)Bv + off);
      }
      #pragma unroll
      for (int am = 0; am < 4; am++)
        #pragma unroll
        for (int an = 0; an < 2; an++) {
          acc_h[am][an] = __builtin_amdgcn_mfma_f32_16x16x32_bf16(af[am], bwf[an], acc_h[am][an], 0, 0, 0);
          acc_v[am][an] = __builtin_amdgcn_mfma_f32_16x16x32_bf16(af[am], bvf[an], acc_v[am][an], 0, 0, 0);
        }
    }
    __syncthreads();
    if (!last) { WRITEB(); }
    __syncthreads();
    cur ^= 1;
  }

  // epilogue: G = silu(h) * v
  #pragma unroll
  for (int am = 0; am < 4; am++) {
    #pragma unroll
    for (int j = 0; j < 4; j++) {
      int m = wr * 64 + am * 16 + fq * 4 + j;
      if (m < nr) {
        ushort* grow = G + (size_t)(g0 + m) * FFN + n0 + wc * 32 + fr;
        #pragma unroll
        for (int an = 0; an < 2; an++) {
          float h = acc_h[am][an][j];
          float v = acc_v[am][an][j];
          float g = h / (1.0f + __expf(-h)) * v;
          grow[an * 16] = f2bf(g);
        }
      }
    }
  }
  #undef LOADB
  #undef WRITEB
}

// ---------------- GEMM2: out += gate * (G w2) ----------------
__global__ __launch_bounds__(512, 4) void mlp2_kernel(
    const ushort* __restrict__ G, const float* __restrict__ w2,
    const int* __restrict__ tiles, const int* __restrict__ ntiles,
    const int* __restrict__ token_flat, const float* __restrict__ gate_flat,
    float* __restrict__ out) {
  int id = blockIdx.x;
  int wg = (id & 7) * CHUNK2 + (id >> 3);
  int tile = wg % MAXT, nblk = wg / MAXT;
  if (tile >= *ntiles) return;
  const int e  = tiles[tile * 3 + 0];
  const int g0 = tiles[tile * 3 + 1];
  const int nr = tiles[tile * 3 + 2];
  const int n0 = nblk * BN;

  __shared__ __align__(16) ushort As[2][BM * BK];  // 2 x 32 KB
  __shared__ __align__(16) ushort Bs[BN * BK];     // 8 KB

  const int tid = threadIdx.x, lane = tid & 63, wv = tid >> 6;
  const int wr = wv >> 1, wc = wv & 1;
  const int fr = lane & 15, fq = lane >> 4;

  uint aoff[4];
  int aslot[4];
  #pragma unroll
  for (int i = 0; i < 4; i++) {
    int slot = i * 512 + tid;
    int m = slot >> 3, g = slot & 7;
    int r = m < nr ? m : (nr - 1);
    aoff[i] = (uint)((g0 + r) * FFN + ((g ^ swz(m)) << 3));
    aslot[i] = slot * 8;
  }

  // B: 512 threads, each 2 k-rows x 4 n-cols
  const int bnq = tid & 15, bkq2 = tid >> 4;  // bkq2 in 0..31, k = bkq2*2 + {0,1}
  const float* bsrc = w2 + (size_t)e * FFN * HID + (size_t)(bkq2 * 2) * HID + n0 + bnq * 4;
  uint boff[4];
  #pragma unroll
  for (int c = 0; c < 4; c++) {
    int n = bnq * 4 + c;
    int k = bkq2 * 2;
    boff[c] = (uint)(n * 128 + (((k >> 3) ^ swz(n)) << 4) + ((k & 7) << 1));
  }

  float4 br0, br1;
  #define LOADB2(k0) { size_t kb = (size_t)(k0) * HID; \
      br0 = *(const float4*)(bsrc + kb); br1 = *(const float4*)(bsrc + kb + HID); }
  #define WRITEB2() { const float* rr[2] = {(const float*)&br0, (const float*)&br1}; \
      _Pragma("unroll") for (int c = 0; c < 4; c++) { \
        union { ushort u[2]; uint v; } p; \
        p.u[0] = f2bf(rr[0][c]); p.u[1] = f2bf(rr[1][c]); \
        *(uint*)((char*)Bs + boff[c]) = p.v; } }

  LOADB2(0);
  #pragma unroll
  for (int i = 0; i < 4; i++)
    gload_lds16(G + aoff[i], &As[0][aslot[i]]);
  WRITEB2();
  __syncthreads();

  f32x4 acc[4][2] = {};
  int cur = 0;

  for (int t = 0; t < FFN / BK; t++) {
    const int last = (t == FFN / BK - 1);
    if (!last) {
      int kn = (t + 1) * BK;
      LOADB2(kn);
      ushort* abase = &As[cur ^ 1][0];
      #pragma unroll
      for (int i = 0; i < 4; i++)
        gload_lds16(G + aoff[i] + kn, abase + aslot[i]);
    }
    const char* Ab = (const char*)&As[cur][0];
    #pragma unroll
    for (int hk = 0; hk < 2; hk++) {
      bf16x8 af[4], bf_[2];
      #pragma unroll
      for (int am = 0; am < 4; am++) {
        int m = wr * 64 + am * 16 + fr;
        af[am] = *(const bf16x8*)(Ab + m * 128 + (((hk * 4 + fq) ^ swz(m)) << 4));
      }
      #pragma unroll
      for (int an = 0; an < 2; an++) {
        int n = wc * 32 + an * 16 + fr;
        bf_[an] = *(const bf16x8*)((const char*)Bs + n * 128 + (((hk * 4 + fq) ^ swz(n)) << 4));
      }
      #pragma unroll
      for (int am = 0; am < 4; am++)
        #pragma unroll
        for (int an = 0; an < 2; an++)
          acc[am][an] = __builtin_amdgcn_mfma_f32_16x16x32_bf16(af[am], bf_[an], acc[am][an], 0, 0, 0);
    }
    __syncthreads();
    if (!last) { WRITEB2(); }
    __syncthreads();
    cur ^= 1;
  }

  #pragma unroll
  for (int am = 0; am < 4; am++) {
    #pragma unroll
    for (int j = 0; j < 4; j++) {
      int m = wr * 64 + am * 16 + fq * 4 + j;
      if (m < nr) {
        float gate = gate_flat[g0 + m];
        int tok = token_flat[g0 + m];
        float* orow = out + (size_t)tok * HID + n0 + wc * 32 + fr;
        #pragma unroll
        for (int an = 0; an < 2; an++)
          atomicAdd(&orow[an * 16], acc[am][an][j] * gate);
      }
    }
  }
  #undef LOADB2
  #undef WRITEB2
}

// ---------------- launch ----------------
extern "C" void kernel_launch(void* const* d_in, const int* in_sizes, int n_in,
                              void* d_out, int out_size, void* d_ws, size_t ws_size,
                              hipStream_t stream) {
  const float* x  = (const float*)d_in[0];
  const float* rw = (const float*)d_in[1];
  const float* w1 = (const float*)d_in[2];
  const float* v1 = (const float*)d_in[3];
  const float* w2 = (const float*)d_in[4];
  float* out0 = (float*)d_out;
  float* wout = out0 + (size_t)NTOK * HID;

  char* ws = (char*)d_ws;
  float* combine    = (float*)(ws + 0);
  int*   counts     = (int*)(ws + 131072);
  int*   seg_off    = (int*)(ws + 131200);
  int*   ntiles     = (int*)(ws + 131328);
  int*   tiles      = (int*)(ws + 131392);
  int*   token_flat = (int*)(ws + 132352);
  float* gate_flat  = (float*)(ws + 165120);
  ushort* G         = (ushort*)(ws + 262144);                               // 64 MB
  ushort* xbf       = (ushort*)(ws + 262144 + (size_t)TOTROWS * FFN * 2);   // 8 MB

  hipMemsetAsync(d_out, 0, (size_t)out_size * sizeof(float), stream);
  init_kernel<<<1, 64, 0, stream>>>(counts);
  cvt_x_kernel<<<(NTOK * HID / 4) / 256, 256, 0, stream>>>(x, (ushort*)xbf);
  router_kernel<<<NTOK, 256, 0, stream>>>(x, rw, wout, combine, counts);
  build_tiles_kernel<<<1, 1, 0, stream>>>(counts, seg_off, tiles, ntiles);
  assign_kernel<<<NE, 256, 0, stream>>>(combine, seg_off, token_flat, gate_flat);
  mlp1_kernel<<<GRID1, 512, 0, stream>>>(xbf, w1, v1, tiles, ntiles, token_flat, G);
  mlp2_kernel<<<GRID2, 512, 0, stream>>>(G, w2, tiles, ntiles, token_flat, gate_flat, out0);
}